// Round 1
// baseline (350.543 us; speedup 1.0000x reference)
//
#include <hip/hip_runtime.h>

// ---------------- problem constants ----------------
constexpr int NB    = 32;
constexpr int HW0   = 320 * 320;          // 102400
constexpr int HW1   = 160 * 160;          // 25600
constexpr int N0    = NB * HW0;           // 3,276,800
constexpr int N1    = NB * HW1;           // 819,200
constexpr int N0_4  = N0 / 4;             // 819,200
constexpr int N1_4  = N1 / 4;             // 204,800
constexpr int HW0_4 = HW0 / 4;            // 25,600
constexpr int HW1_4 = HW1 / 4;            // 6,400

constexpr int GRID = 1024;
constexpr int BLK  = 256;

// ---------------- workspace layout ----------------
// [0,256)        : BranchCtrl[2] (128 B each)
// [1024, 66560)  : per branch 4 histograms x 2048 u32 (histA, histB, h2, h3)
// [66560,164864) : per branch partial arrays (pos,neg,cnt u32[1024]; ce0,d2,ms,ce1 f64[1024])
// [262144, ...)  : packed p_neg bits (branch0 then branch1), optional
constexpr size_t CTRL_OFF    = 0;
constexpr size_t HIST_OFF    = 1024;
constexpr size_t HIST_BR     = 4 * 2048 * 4;           // 32768
constexpr size_t PART_OFF    = HIST_OFF + 2 * HIST_BR; // 66560
constexpr size_t PART_BR     = 49152;
constexpr size_t PNEG_OFF    = 262144;
constexpr size_t PNEG_NEED   = PNEG_OFF + (size_t)(N0 + N1) * 4;  // 16,646,144
constexpr int    ZERO_WORDS  = (int)((HIST_OFF + 2 * HIST_BR) / 4); // 16,640

struct BranchCtrl {
    unsigned pos_num;
    unsigned neg_num;
    unsigned sel1;
    unsigned sel2;
    unsigned thr_bits;
    unsigned target;     // remaining 1-based rank within current selection
    unsigned _pu[2];
    double   ce0, d2, ms;
    double   _pd[9];     // pad to 128 B
};

__host__ __device__ inline BranchCtrl* ctrl_of(void* ws, int b) {
    return (BranchCtrl*)((char*)ws + CTRL_OFF) + b;
}
__host__ __device__ inline unsigned* hist_of(void* ws, int b, int which) {
    return (unsigned*)((char*)ws + HIST_OFF + (size_t)b * HIST_BR + (size_t)which * 2048 * 4);
}
// which: 0=pos,1=neg,2=cnt
__host__ __device__ inline unsigned* upart(void* ws, int b, int which) {
    return (unsigned*)((char*)ws + PART_OFF + (size_t)b * PART_BR + (size_t)which * 4096);
}
// which: 0=ce0,1=d2,2=ms,3=ce1
__host__ __device__ inline double* dpart(void* ws, int b, int which) {
    return (double*)((char*)ws + PART_OFF + (size_t)b * PART_BR + 16384 + (size_t)which * 8192);
}
__host__ __device__ inline unsigned* pneg_of(void* ws, int b) {
    return (unsigned*)((char*)ws + PNEG_OFF + (b ? (size_t)N0 * 4 : 0));
}

// ---------------- device helpers ----------------
__device__ __forceinline__ void softmax2(float a, float c, float& p0, float& p1) {
    float m  = fmaxf(a, c);
    float e0 = expf(a - m);
    float e1 = expf(c - m);
    float inv = 1.0f / (e0 + e1);
    p0 = e0 * inv;
    p1 = e1 * inv;
}

template <typename T>
__device__ __forceinline__ T block_reduce(T v, T* scr) {
#pragma unroll
    for (int o = 32; o > 0; o >>= 1) v += __shfl_down(v, o, 64);
    const int lane = threadIdx.x & 63;
    const int w    = threadIdx.x >> 6;
    __syncthreads();                 // protect scratch reuse across calls
    if (lane == 0) scr[w] = v;
    __syncthreads();
    return scr[0] + scr[1] + scr[2] + scr[3];
}

// ---------------- kernels ----------------
__global__ __launch_bounds__(256) void zero_ws_k(unsigned* p, int n) {
    int i = blockIdx.x * BLK + threadIdx.x;
    if (i < n) p[i] = 0;
}

template <bool STORED>
__global__ __launch_bounds__(256) void main_pass(
    const float4* __restrict__ score, const float4* __restrict__ bbox,
    const float4* __restrict__ gmask, const float4* __restrict__ glabel,
    void* ws, int branch, int N4, int HW4)
{
    __shared__ unsigned hA[2048];
    __shared__ unsigned hB[2048];
    for (int i = threadIdx.x; i < 2048; i += BLK) { hA[i] = 0; hB[i] = 0; }
    __syncthreads();

    unsigned* pn_out = pneg_of(ws, branch);
    unsigned posc = 0, negc = 0;
    double ce0 = 0.0, d2 = 0.0, ms = 0.0;

    for (int i = blockIdx.x * BLK + threadIdx.x; i < N4; i += GRID * BLK) {
        const int b = i / HW4;
        const int r = i - b * HW4;
        const float4 s0 = score[(b * 2 + 0) * HW4 + r];
        const float4 s1 = score[(b * 2 + 1) * HW4 + r];
        const float4 g0 = glabel[(b * 6 + 0) * HW4 + r];
        const float4 g1 = glabel[(b * 6 + 1) * HW4 + r];
        uint4 pk;
        unsigned* pkp = &pk.x;
#pragma unroll
        for (int j = 0; j < 4; j++) {
            float p0, p1;
            softmax2((&s0.x)[j], (&s1.x)[j], p0, p1);
            float l0 = (&g0.x)[j], l1 = (&g1.x)[j];
            bool pos = l0 > 0.5f;
            bool neg = l1 > 0.5f;
            posc += pos ? 1u : 0u;
            negc += neg ? 1u : 0u;
            if (pos) ce0 += (double)(-l0 * logf(p0));
            unsigned pb = __float_as_uint(p1);
            pkp[j] = pb | (neg ? 0x80000000u : 0u);
            if (neg) atomicAdd(&hA[pb >> 21], 1u);
            else     atomicAdd(&hB[pb >> 21], 1u);
        }
        if (STORED) ((uint4*)pn_out)[i] = pk;
#pragma unroll
        for (int cch = 0; cch < 4; cch++) {
            const float4 pb4 = bbox[(b * 4 + cch) * HW4 + r];
            const float4 gm4 = gmask[(b * 6 + 2 + cch) * HW4 + r];
            const float4 gl4 = glabel[(b * 6 + 2 + cch) * HW4 + r];
#pragma unroll
            for (int j = 0; j < 4; j++) {
                float mval = (&gm4.x)[j];
                float d = ((&pb4.x)[j] - (&gl4.x)[j]) * mval;
                d2 += (double)(d * d);
                ms += (double)mval;
            }
        }
    }
    __syncthreads();
    unsigned* gA = hist_of(ws, branch, 0);
    unsigned* gB = hist_of(ws, branch, 1);
    for (int i = threadIdx.x; i < 2048; i += BLK) {
        if (hA[i]) atomicAdd(&gA[i], hA[i]);
        if (hB[i]) atomicAdd(&gB[i], hB[i]);
    }
    __shared__ double dscr[4];
    __shared__ unsigned uscr[4];
    double CE0 = block_reduce(ce0, dscr);
    double D2  = block_reduce(d2, dscr);
    double MS  = block_reduce(ms, dscr);
    unsigned P = block_reduce(posc, uscr);
    unsigned Nn = block_reduce(negc, uscr);
    if (threadIdx.x == 0) {
        dpart(ws, branch, 0)[blockIdx.x] = CE0;
        dpart(ws, branch, 1)[blockIdx.x] = D2;
        dpart(ws, branch, 2)[blockIdx.x] = MS;
        upart(ws, branch, 0)[blockIdx.x] = P;
        upart(ws, branch, 1)[blockIdx.x] = Nn;
    }
}

// one block per branch; level in {1,2,3}
__global__ __launch_bounds__(256) void scan_pass(void* ws, int level) {
    const int br = blockIdx.x;
    BranchCtrl* c = ctrl_of(ws, br);
    const int N = br ? N1 : N0;
    const int t = threadIdx.x;
    __shared__ double dscr[4];
    __shared__ unsigned uscr[4];
    __shared__ unsigned pref[256];

    unsigned target, haspos, negn;
    if (level == 1) {
        unsigned p = 0, n = 0;
        double ce0 = 0, d2 = 0, ms = 0;
        for (int i = t; i < GRID; i += BLK) {
            p   += upart(ws, br, 0)[i];
            n   += upart(ws, br, 1)[i];
            ce0 += dpart(ws, br, 0)[i];
            d2  += dpart(ws, br, 1)[i];
            ms  += dpart(ws, br, 2)[i];
        }
        unsigned P  = block_reduce(p, uscr);
        unsigned Nn = block_reduce(n, uscr);
        double CE0  = block_reduce(ce0, dscr);
        double D2   = block_reduce(d2, dscr);
        double MS   = block_reduce(ms, dscr);
        if (t == 0) {
            c->pos_num = P; c->neg_num = Nn;
            c->ce0 = CE0; c->d2 = D2; c->ms = MS;
        }
        haspos = (P > 0) ? 1u : 0u;
        negn = Nn;
        unsigned k = haspos ? ((5u * P < Nn) ? 5u * P : Nn) : (unsigned)(N / 10);
        long rank = (long)k - 1;
        if (rank < 0) rank = 0;
        if (rank > (long)N - 1) rank = (long)N - 1;
        target = (unsigned)(rank + 1);
    } else {
        target = c->target;
        haspos = (c->pos_num > 0) ? 1u : 0u;
        negn   = c->neg_num;
    }

    const unsigned* hAg = hist_of(ws, br, 0);
    const unsigned* hBg = hist_of(ws, br, 1);
    const unsigned* hg  = hist_of(ws, br, (level == 2) ? 2 : 3);
    const int nb  = (level == 3) ? 1024 : 2048;
    const int per = nb / BLK;   // 4 or 8

    unsigned v[8];
    unsigned s = 0;
    for (int j = 0; j < per; j++) {
        int i = t * per + j;
        unsigned x;
        if (level == 1)
            x = haspos ? (hAg[i] + (i == 0 ? (unsigned)N - negn : 0u)) : (hAg[i] + hBg[i]);
        else
            x = hg[i];
        v[j] = x;
        s += x;
    }
    __syncthreads();
    pref[t] = s;
    __syncthreads();
    for (int off = 1; off < 256; off <<= 1) {
        unsigned x = (t >= off) ? pref[t - off] : 0u;
        __syncthreads();
        pref[t] += x;
        __syncthreads();
    }
    unsigned tot = pref[255];
    if (tot > 0 && target > tot) target = tot;   // robustness clamp
    unsigned before = pref[t] - s;
    for (int j = 0; j < per; j++) {
        unsigned bin = (unsigned)(t * per + j);
        if (before < target && before + v[j] >= target) {
            if (level == 1)      { c->sel1 = bin; c->target = target - before; }
            else if (level == 2) { c->sel2 = bin; c->target = target - before; }
            else                 { c->thr_bits = (c->sel1 << 21) | (c->sel2 << 10) | bin; }
        }
        before += v[j];
    }
}

template <bool STORED>
__global__ __launch_bounds__(256) void hist_refine(
    const float4* __restrict__ score, const float4* __restrict__ glabel,
    void* ws, int branch, int level, int N4, int HW4)
{
    __shared__ unsigned h[2048];
    for (int i = threadIdx.x; i < 2048; i += BLK) h[i] = 0;
    __syncthreads();

    BranchCtrl* c = ctrl_of(ws, branch);
    const unsigned haspos = (c->pos_num > 0) ? 1u : 0u;
    const unsigned sel  = (level == 2) ? c->sel1 : ((c->sel1 << 11) | c->sel2);
    const int scmp      = (level == 2) ? 21 : 10;
    const int sbin      = (level == 2) ? 10 : 0;
    const unsigned bmsk = (level == 2) ? 0x7FFu : 0x3FFu;
    const uint4* pn = (const uint4*)pneg_of(ws, branch);

    for (int i = blockIdx.x * BLK + threadIdx.x; i < N4; i += GRID * BLK) {
        unsigned pk[4];
        if (STORED) {
            uint4 q = pn[i];
            pk[0] = q.x; pk[1] = q.y; pk[2] = q.z; pk[3] = q.w;
        } else {
            const int b = i / HW4;
            const int r = i - b * HW4;
            const float4 s0 = score[(b * 2 + 0) * HW4 + r];
            const float4 s1 = score[(b * 2 + 1) * HW4 + r];
            const float4 g1 = glabel[(b * 6 + 1) * HW4 + r];
#pragma unroll
            for (int j = 0; j < 4; j++) {
                float p0, p1;
                softmax2((&s0.x)[j], (&s1.x)[j], p0, p1);
                pk[j] = __float_as_uint(p1) | (((&g1.x)[j] > 0.5f) ? 0x80000000u : 0u);
            }
        }
#pragma unroll
        for (int j = 0; j < 4; j++) {
            unsigned pb  = pk[j] & 0x7FFFFFFFu;
            unsigned npb = haspos ? ((pk[j] >> 31) ? pb : 0u) : pb;
            if ((npb >> scmp) == sel) atomicAdd(&h[(npb >> sbin) & bmsk], 1u);
        }
    }
    __syncthreads();
    unsigned* gh = hist_of(ws, branch, (level == 2) ? 2 : 3);
    for (int i = threadIdx.x; i < 2048; i += BLK)
        if (h[i]) atomicAdd(&gh[i], h[i]);
}

template <bool STORED>
__global__ __launch_bounds__(256) void final_ce(
    const float4* __restrict__ score, const float4* __restrict__ glabel,
    void* ws, int branch, int N4, int HW4)
{
    BranchCtrl* c = ctrl_of(ws, branch);
    const unsigned haspos = (c->pos_num > 0) ? 1u : 0u;
    const unsigned thr = c->thr_bits;
    const uint4* pn = (const uint4*)pneg_of(ws, branch);

    unsigned cnt = 0;
    double ce1 = 0.0;
    for (int i = blockIdx.x * BLK + threadIdx.x; i < N4; i += GRID * BLK) {
        const int b = i / HW4;
        const int r = i - b * HW4;
        const float4 g1 = glabel[(b * 6 + 1) * HW4 + r];
        unsigned pk[4];
        if (STORED) {
            uint4 q = pn[i];
            pk[0] = q.x; pk[1] = q.y; pk[2] = q.z; pk[3] = q.w;
        } else {
            const float4 s0 = score[(b * 2 + 0) * HW4 + r];
            const float4 s1 = score[(b * 2 + 1) * HW4 + r];
#pragma unroll
            for (int j = 0; j < 4; j++) {
                float p0, p1;
                softmax2((&s0.x)[j], (&s1.x)[j], p0, p1);
                pk[j] = __float_as_uint(p1) | (((&g1.x)[j] > 0.5f) ? 0x80000000u : 0u);
            }
        }
#pragma unroll
        for (int j = 0; j < 4; j++) {
            unsigned pb  = pk[j] & 0x7FFFFFFFu;
            unsigned npb = haspos ? ((pk[j] >> 31) ? pb : 0u) : pb;
            if (npb <= thr) {
                cnt++;
                ce1 += (double)(-(&g1.x)[j] * logf(__uint_as_float(pb)));
            }
        }
    }
    __shared__ double dscr[4];
    __shared__ unsigned uscr[4];
    double CE1 = block_reduce(ce1, dscr);
    unsigned CNT = block_reduce(cnt, uscr);
    if (threadIdx.x == 0) {
        dpart(ws, branch, 3)[blockIdx.x] = CE1;
        upart(ws, branch, 2)[blockIdx.x] = CNT;
    }
}

__global__ __launch_bounds__(256) void finalize_k(void* ws, float* out) {
    __shared__ double dscr[4];
    __shared__ unsigned uscr[4];
    double ce1tot[2];
    unsigned cnttot[2];
    for (int br = 0; br < 2; br++) {
        double ce = 0.0;
        unsigned cn = 0;
        for (int i = threadIdx.x; i < GRID; i += BLK) {
            ce += dpart(ws, br, 3)[i];
            cn += upart(ws, br, 2)[i];
        }
        ce1tot[br] = block_reduce(ce, dscr);
        cnttot[br] = block_reduce(cn, uscr);
    }
    if (threadIdx.x == 0) {
        double ls[2], lb[2];
        for (int br = 0; br < 2; br++) {
            BranchCtrl* c = ctrl_of(ws, br);
            double cnt = (double)c->pos_num + (double)cnttot[br];
            if (cnt < 1.0) cnt = 1.0;
            ls[br] = (c->ce0 + ce1tot[br]) / cnt;
            lb[br] = (c->ms > 0.0) ? (c->d2 / fmax(c->ms, 1e-8)) : 0.0;
        }
        out[0] = (float)(ls[0] + lb[0] + ls[1] + lb[1]);
        out[1] = (float)ls[0];
        out[2] = (float)lb[0];
        out[3] = (float)ls[1];
        out[4] = (float)lb[1];
    }
}

// ---------------- host ----------------
template <bool S>
static void run_pipeline(const float4* sc0, const float4* bb0, const float4* mk0, const float4* lb0,
                         const float4* sc1, const float4* bb1, const float4* mk1, const float4* lb1,
                         void* ws, float* out, hipStream_t stream)
{
    main_pass<S><<<GRID, BLK, 0, stream>>>(sc0, bb0, mk0, lb0, ws, 0, N0_4, HW0_4);
    main_pass<S><<<GRID, BLK, 0, stream>>>(sc1, bb1, mk1, lb1, ws, 1, N1_4, HW1_4);
    scan_pass<<<2, BLK, 0, stream>>>(ws, 1);
    hist_refine<S><<<GRID, BLK, 0, stream>>>(sc0, lb0, ws, 0, 2, N0_4, HW0_4);
    hist_refine<S><<<GRID, BLK, 0, stream>>>(sc1, lb1, ws, 1, 2, N1_4, HW1_4);
    scan_pass<<<2, BLK, 0, stream>>>(ws, 2);
    hist_refine<S><<<GRID, BLK, 0, stream>>>(sc0, lb0, ws, 0, 3, N0_4, HW0_4);
    hist_refine<S><<<GRID, BLK, 0, stream>>>(sc1, lb1, ws, 1, 3, N1_4, HW1_4);
    scan_pass<<<2, BLK, 0, stream>>>(ws, 3);
    final_ce<S><<<GRID, BLK, 0, stream>>>(sc0, lb0, ws, 0, N0_4, HW0_4);
    final_ce<S><<<GRID, BLK, 0, stream>>>(sc1, lb1, ws, 1, N1_4, HW1_4);
    finalize_k<<<1, BLK, 0, stream>>>(ws, out);
}

extern "C" void kernel_launch(void* const* d_in, const int* in_sizes, int n_in,
                              void* d_out, int out_size, void* d_ws, size_t ws_size,
                              hipStream_t stream)
{
    (void)in_sizes; (void)n_in; (void)out_size;
    const float4* sc0 = (const float4*)d_in[0];
    const float4* bb0 = (const float4*)d_in[1];
    const float4* mk0 = (const float4*)d_in[2];
    const float4* lb0 = (const float4*)d_in[3];
    const float4* sc1 = (const float4*)d_in[4];
    const float4* bb1 = (const float4*)d_in[5];
    const float4* mk1 = (const float4*)d_in[6];
    const float4* lb1 = (const float4*)d_in[7];
    float* out = (float*)d_out;

    zero_ws_k<<<(ZERO_WORDS + BLK - 1) / BLK, BLK, 0, stream>>>((unsigned*)d_ws, ZERO_WORDS);

    if (ws_size >= PNEG_NEED)
        run_pipeline<true>(sc0, bb0, mk0, lb0, sc1, bb1, mk1, lb1, d_ws, out, stream);
    else
        run_pipeline<false>(sc0, bb0, mk0, lb0, sc1, bb1, mk1, lb1, d_ws, out, stream);
}

// Round 2
// 337.347 us; speedup vs baseline: 1.0391x; 1.0391x over previous
//
#include <hip/hip_runtime.h>

// ---------------- problem constants ----------------
constexpr int NB    = 32;
constexpr int HW0   = 320 * 320;          // 102400
constexpr int HW1   = 160 * 160;          // 25600
constexpr int N0    = NB * HW0;           // 3,276,800
constexpr int N1    = NB * HW1;           // 819,200
constexpr int HW0_4 = HW0 / 4;            // 25,600
constexpr int HW1_4 = HW1 / 4;            // 6,400
constexpr int N0_4  = N0 / 4;             // 819,200
constexpr int N1_4  = N1 / 4;             // 204,800
constexpr int BLK   = 256;
constexpr int NBLK0 = N0_4 / BLK;         // 3200
constexpr int NBLK1 = N1_4 / BLK;         // 800
constexpr int GRID_M = NBLK0 + NBLK1;     // 4000 (one float4-pack per thread)
constexpr int RB0   = NBLK0 / 2;          // 1600 (refine: 2 packs per thread)
constexpr int RB1   = NBLK1 / 2;          // 400
constexpr int GRID_R = RB0 + RB1;         // 2000

constexpr unsigned long long MASK40 = (1ull << 40) - 1;
constexpr float CE_SCALE = 65536.0f;      // fixed-point 2^16 for CE sums

// radix levels: bits [31:21] (<=507 since p1<1), [20:10], [9:0]
constexpr int L1B = 512, L2B = 2048, L3B = 1024;

// ---------------- workspace layout ----------------
// u32 hists per branch (u32 units): hA[0,512) hB[512,1024) h2[1024,3072) h3[3072,4096)
// u64 ce hists mirror the same layout in u64 units.
constexpr size_t CTRL_OFF = 0;                          // BranchCtrl[2], 256 B
constexpr size_t U32H_OFF = 1024;
constexpr size_t U64H_OFF = U32H_OFF + 2 * 4096 * 4;    // 33792
constexpr size_t PART_OFF = U64H_OFF + 2 * 4096 * 8;    // 99328
constexpr size_t PART_BR  = 3200 * (4 + 4) + 3200 * (8 + 8 + 8); // 102400
constexpr size_t PB_OFF   = 524288;                     // u32[N0+N1] packed p1 bits | negflag<<31
constexpr size_t CE_OFF   = PB_OFF + (size_t)(N0 + N1) * 4;      // f32[N0+N1] -g1*log(p1)
constexpr size_t WS_NEED  = CE_OFF + (size_t)(N0 + N1) * 4;      // ~33.3 MB
constexpr int    ZERO_WORDS = (int)(PART_OFF / 4);      // 24832

struct BranchCtrl {
    unsigned pos_num, neg_num, sel1, sel2;
    unsigned target, cnt_below, pad0, pad1;
    unsigned long long ce_below_fx;
    double ce0, d2, ms;
    double loss_score, loss_bbox;
    double pad2[6];   // -> 128 B
};

__device__ inline BranchCtrl* ctrl_of(void* ws, int br) { return (BranchCtrl*)((char*)ws + CTRL_OFF) + br; }
__device__ inline unsigned* u32h(void* ws, int br) { return (unsigned*)((char*)ws + U32H_OFF) + (size_t)br * 4096; }
__device__ inline unsigned long long* u64h(void* ws, int br) { return (unsigned long long*)((char*)ws + U64H_OFF) + (size_t)br * 4096; }
__device__ inline unsigned* part_u32(void* ws, int br, int w) { return (unsigned*)((char*)ws + PART_OFF + (size_t)br * PART_BR) + (size_t)w * 3200; }
__device__ inline double* part_f64(void* ws, int br, int w) { return (double*)((char*)ws + PART_OFF + (size_t)br * PART_BR + 25600) + (size_t)w * 3200; }
__device__ inline unsigned* pb_of(void* ws, int br) { return (unsigned*)((char*)ws + PB_OFF) + (br ? (size_t)N0 : 0); }
__device__ inline float* ce_of(void* ws, int br) { return (float*)((char*)ws + CE_OFF) + (br ? (size_t)N0 : 0); }

// ---------------- device helpers ----------------
__device__ __forceinline__ void softmax2(float a, float c, float& p0, float& p1) {
    float m  = fmaxf(a, c);
    float e0 = expf(a - m);
    float e1 = expf(c - m);
    float inv = 1.0f / (e0 + e1);
    p0 = e0 * inv;
    p1 = e1 * inv;
}

template <typename T>
__device__ __forceinline__ T block_reduce(T v, T* scr) {
#pragma unroll
    for (int o = 32; o > 0; o >>= 1) v += __shfl_down(v, o, 64);
    const int lane = threadIdx.x & 63;
    const int w    = threadIdx.x >> 6;
    __syncthreads();
    if (lane == 0) scr[w] = v;
    __syncthreads();
    return scr[0] + scr[1] + scr[2] + scr[3];
}

// ---------------- kernels ----------------
__global__ __launch_bounds__(256) void zero_ws_k(unsigned* p, int n) {
    int i = blockIdx.x * BLK + threadIdx.x;
    if (i < n) p[i] = 0;
}

// Main fused pass: one float4-pack (4 pixels) per thread, all loads issued up-front.
template <int BR, bool STORED>
__device__ void main_body(const float4* __restrict__ score, const float4* __restrict__ bbox,
                          const float4* __restrict__ gmask, const float4* __restrict__ glabel,
                          void* ws, int blk, unsigned long long* hAB)
{
    constexpr int HW4 = BR ? HW1_4 : HW0_4;
    const int idx = blk * BLK + (int)threadIdx.x;
    const int b = idx / HW4;           // compile-time divisor -> magic mul
    const int r = idx - b * HW4;

    // ---- issue ALL 16 independent loads ----
    const float4 s0 = score[(b * 2 + 0) * HW4 + r];
    const float4 s1 = score[(b * 2 + 1) * HW4 + r];
    const float4 g0 = glabel[(b * 6 + 0) * HW4 + r];
    const float4 g1 = glabel[(b * 6 + 1) * HW4 + r];
    float4 pbv[4], gmv[4], glv[4];
#pragma unroll
    for (int c = 0; c < 4; c++) {
        pbv[c] = bbox[(b * 4 + c) * HW4 + r];
        gmv[c] = gmask[(b * 6 + 2 + c) * HW4 + r];
        glv[c] = glabel[(b * 6 + 2 + c) * HW4 + r];
    }

    // ---- score part ----
    unsigned posc = 0, negc = 0;
    float ce0f = 0.0f;
    uint4 pk; float4 cef;
    unsigned* pkp = &pk.x; float* cep = &cef.x;
#pragma unroll
    for (int j = 0; j < 4; j++) {
        float p0, p1;
        softmax2((&s0.x)[j], (&s1.x)[j], p0, p1);
        float l0 = (&g0.x)[j], l1 = (&g1.x)[j];
        bool pos = l0 > 0.5f;
        bool neg = l1 > 0.5f;
        posc += pos ? 1u : 0u;
        negc += neg ? 1u : 0u;
        ce0f += pos ? (-l0 * logf(p0)) : 0.0f;
        float cv = -l1 * logf(p1);
        unsigned pb = __float_as_uint(p1);
        pkp[j] = pb | (neg ? 0x80000000u : 0u);
        cep[j] = cv;
        unsigned long long val = (1ull << 40) | (unsigned long long)__float2uint_rn(cv * CE_SCALE);
        atomicAdd(&hAB[(neg ? 0 : 512) + (pb >> 21)], val);
    }
    if (STORED) {
        ((uint4*)pb_of(ws, BR))[idx] = pk;
        ((float4*)ce_of(ws, BR))[idx] = cef;
    }

    // ---- bbox part ----
    float d2f = 0.0f, msf = 0.0f;
#pragma unroll
    for (int c = 0; c < 4; c++) {
#pragma unroll
        for (int j = 0; j < 4; j++) {
            float mval = (&gmv[c].x)[j];
            float d = ((&pbv[c].x)[j] - (&glv[c].x)[j]) * mval;
            d2f += d * d;
            msf += mval;
        }
    }

    __shared__ double dscr[4];
    __shared__ unsigned uscr[4];
    double CE0 = block_reduce((double)ce0f, dscr);
    double D2  = block_reduce((double)d2f, dscr);
    double MS  = block_reduce((double)msf, dscr);
    unsigned P  = block_reduce(posc, uscr);
    unsigned Nn = block_reduce(negc, uscr);
    if (threadIdx.x == 0) {
        part_u32(ws, BR, 0)[blk] = P;
        part_u32(ws, BR, 1)[blk] = Nn;
        part_f64(ws, BR, 0)[blk] = CE0;
        part_f64(ws, BR, 1)[blk] = D2;
        part_f64(ws, BR, 2)[blk] = MS;
    }
}

template <bool STORED>
__global__ __launch_bounds__(256) void main_pass(
    const float4* __restrict__ sc0, const float4* __restrict__ bb0,
    const float4* __restrict__ mk0, const float4* __restrict__ lb0,
    const float4* __restrict__ sc1, const float4* __restrict__ bb1,
    const float4* __restrict__ mk1, const float4* __restrict__ lb1,
    void* ws)
{
    __shared__ unsigned long long hAB[1024];   // [0,512)=neg by pb>>21, [512,1024)=non-neg
    for (int i = threadIdx.x; i < 1024; i += BLK) hAB[i] = 0;
    __syncthreads();

    int br, blk;
    if (blockIdx.x < NBLK0) { br = 0; blk = blockIdx.x;        main_body<0, STORED>(sc0, bb0, mk0, lb0, ws, blk, hAB); }
    else                    { br = 1; blk = blockIdx.x - NBLK0; main_body<1, STORED>(sc1, bb1, mk1, lb1, ws, blk, hAB); }

    __syncthreads();
    unsigned* gc = u32h(ws, br);
    unsigned long long* ge = u64h(ws, br);
    for (int i = threadIdx.x; i < 1024; i += BLK) {
        unsigned long long v = hAB[i];
        if (v) {
            atomicAdd(&gc[i], (unsigned)(v >> 40));
            atomicAdd(&ge[i], v & MASK40);
        }
    }
}

// Refine pass: histogram (count + ce) of elements inside the selected prefix bin.
template <int BR, bool STORED>
__device__ void refine_body(const float4* __restrict__ score, const float4* __restrict__ glabel,
                            void* ws, int blk, int level, unsigned long long* h)
{
    BranchCtrl* c = ctrl_of(ws, BR);
    const unsigned haspos = (c->pos_num > 0) ? 1u : 0u;
    unsigned sel, scmp, sbin, bmsk;
    if (level == 2) { sel = c->sel1;                     scmp = 21; sbin = 10; bmsk = 0x7FFu; }
    else            { sel = (c->sel1 << 11) | c->sel2;   scmp = 10; sbin = 0;  bmsk = 0x3FFu; }

    const int idx0 = blk * (BLK * 2) + (int)threadIdx.x;   // 2 packs/thread, stride BLK
    unsigned pkv[8]; float cev[8];
    if (STORED) {
        const uint4*  pb4 = (const uint4*)pb_of(ws, BR);
        const float4* ce4 = (const float4*)ce_of(ws, BR);
        uint4 q0 = pb4[idx0], q1 = pb4[idx0 + BLK];
        float4 e0 = ce4[idx0], e1 = ce4[idx0 + BLK];
        pkv[0]=q0.x; pkv[1]=q0.y; pkv[2]=q0.z; pkv[3]=q0.w;
        pkv[4]=q1.x; pkv[5]=q1.y; pkv[6]=q1.z; pkv[7]=q1.w;
        cev[0]=e0.x; cev[1]=e0.y; cev[2]=e0.z; cev[3]=e0.w;
        cev[4]=e1.x; cev[5]=e1.y; cev[6]=e1.z; cev[7]=e1.w;
    } else {
        constexpr int HW4 = BR ? HW1_4 : HW0_4;
#pragma unroll
        for (int half = 0; half < 2; half++) {
            int id = idx0 + half * BLK;
            int b = id / HW4;
            int r = id - b * HW4;
            float4 s0 = score[(b * 2 + 0) * HW4 + r];
            float4 s1 = score[(b * 2 + 1) * HW4 + r];
            float4 g1 = glabel[(b * 6 + 1) * HW4 + r];
#pragma unroll
            for (int j = 0; j < 4; j++) {
                float p0, p1;
                softmax2((&s0.x)[j], (&s1.x)[j], p0, p1);
                pkv[half * 4 + j] = __float_as_uint(p1) | (((&g1.x)[j] > 0.5f) ? 0x80000000u : 0u);
                cev[half * 4 + j] = -(&g1.x)[j] * logf(p1);
            }
        }
    }

    unsigned bins[8]; unsigned long long vals[8];
#pragma unroll
    for (int j = 0; j < 8; j++) {
        unsigned raw = pkv[j];
        unsigned pb  = raw & 0x7FFFFFFFu;
        unsigned npb = haspos ? ((raw >> 31) ? pb : 0u) : pb;
        bool m = ((npb >> scmp) == sel);
        bins[j] = m ? ((npb >> sbin) & bmsk) : 0xFFFFFFFFu;
        vals[j] = (1ull << 40) | (unsigned long long)__float2uint_rn(cev[j] * CE_SCALE);
    }
    // in-thread dedup: hot selected bin (e.g. the zeros bin) collapses 8 atomics -> 1
#pragma unroll
    for (int j = 0; j < 8; j++) {
        if (bins[j] != 0xFFFFFFFFu) {
            unsigned long long v = vals[j];
#pragma unroll
            for (int k = j + 1; k < 8; k++)
                if (bins[k] == bins[j]) { v += vals[k]; bins[k] = 0xFFFFFFFFu; }
            atomicAdd(&h[bins[j]], v);
        }
    }
}

template <bool STORED>
__global__ __launch_bounds__(256) void refine_pass(
    const float4* __restrict__ sc0, const float4* __restrict__ lb0,
    const float4* __restrict__ sc1, const float4* __restrict__ lb1,
    void* ws, int level)
{
    __shared__ unsigned long long h[2048];
    const int nb = (level == 2) ? L2B : L3B;
    for (int i = threadIdx.x; i < nb; i += BLK) h[i] = 0;
    __syncthreads();

    int br, blk;
    if (blockIdx.x < RB0) { br = 0; blk = blockIdx.x;       refine_body<0, STORED>(sc0, lb0, ws, blk, level, h); }
    else                  { br = 1; blk = blockIdx.x - RB0; refine_body<1, STORED>(sc1, lb1, ws, blk, level, h); }

    __syncthreads();
    const int goff = (level == 2) ? 1024 : 3072;
    unsigned* gc = u32h(ws, br) + goff;
    unsigned long long* ge = u64h(ws, br) + goff;
    for (int i = threadIdx.x; i < nb; i += BLK) {
        unsigned long long v = h[i];
        if (v) {
            atomicAdd(&gc[i], (unsigned)(v >> 40));
            atomicAdd(&ge[i], v & MASK40);
        }
    }
}

// Single-block scan/select. level=1: also reduces per-block partials. level=3: finalizes output.
__global__ __launch_bounds__(256) void scan_pass(void* ws, int level, float* out) {
    const int t = threadIdx.x;
    __shared__ unsigned pref[256];
    __shared__ double dscr[4];
    __shared__ unsigned uscr[4];
    __shared__ unsigned long long qscr[4];
    __shared__ unsigned sh_sel, sh_tnext, sh_cb, sh_ci;

    for (int br = 0; br < 2; br++) {
        BranchCtrl* c = ctrl_of(ws, br);
        const int N = br ? N1 : N0;
        const int nblk = br ? NBLK1 : NBLK0;
        unsigned target, haspos, negn;

        if (level == 1) {
            unsigned p = 0, n = 0;
            double ce0 = 0, d2 = 0, ms = 0;
            const unsigned* pp = part_u32(ws, br, 0);
            const unsigned* pn = part_u32(ws, br, 1);
            const double* q0 = part_f64(ws, br, 0);
            const double* q1 = part_f64(ws, br, 1);
            const double* q2 = part_f64(ws, br, 2);
            for (int i = t; i < nblk; i += BLK) {
                p += pp[i]; n += pn[i]; ce0 += q0[i]; d2 += q1[i]; ms += q2[i];
            }
            unsigned P  = block_reduce(p, uscr);
            unsigned Nn = block_reduce(n, uscr);
            double CE0  = block_reduce(ce0, dscr);
            double D2   = block_reduce(d2, dscr);
            double MS   = block_reduce(ms, dscr);
            if (t == 0) { c->pos_num = P; c->neg_num = Nn; c->ce0 = CE0; c->d2 = D2; c->ms = MS; }
            haspos = (P > 0) ? 1u : 0u;
            negn = Nn;
            unsigned k = haspos ? ((5u * P < Nn) ? 5u * P : Nn) : (unsigned)(N / 10);
            target = (k < 1u) ? 1u : k;                    // jnp.take clips index -1 -> 0
            if (target > (unsigned)N) target = (unsigned)N;
        } else {
            target = c->target;
            haspos = (c->pos_num > 0) ? 1u : 0u;
            negn = c->neg_num;
        }

        const int nb  = (level == 1) ? L1B : (level == 2) ? L2B : L3B;
        const int per = nb / BLK;   // 2 / 8 / 4

        unsigned long long sumB = 0;
        if (level == 1 && haspos) {
            const unsigned long long* eB = u64h(ws, br) + 512;
            unsigned long long s = 0;
            for (int i = t; i < L1B; i += BLK) s += eB[i];
            sumB = block_reduce(s, qscr);
        }

        unsigned cnt[8]; unsigned long long cev[8];
        unsigned s = 0;
        for (int j = 0; j < per; j++) {
            int i = t * per + j;
            unsigned cv; unsigned long long ev;
            if (level == 1) {
                const unsigned* hA = u32h(ws, br); const unsigned* hB = hA + 512;
                const unsigned long long* eA = u64h(ws, br); const unsigned long long* eB = eA + 512;
                if (haspos) { cv = hA[i] + ((i == 0) ? ((unsigned)N - negn) : 0u); ev = eA[i] + ((i == 0) ? sumB : 0ull); }
                else        { cv = hA[i] + hB[i]; ev = eA[i] + eB[i]; }
            } else if (level == 2) { cv = (u32h(ws, br) + 1024)[i]; ev = (u64h(ws, br) + 1024)[i]; }
            else                   { cv = (u32h(ws, br) + 3072)[i]; ev = (u64h(ws, br) + 3072)[i]; }
            cnt[j] = cv; cev[j] = ev; s += cv;
        }
        __syncthreads();
        pref[t] = s;
        __syncthreads();
        for (int off = 1; off < 256; off <<= 1) {
            unsigned x = (t >= off) ? pref[t - off] : 0u;
            __syncthreads();
            pref[t] += x;
            __syncthreads();
        }
        unsigned tot = pref[255];
        if (target > tot) target = tot;      // safety (tot>0 by construction)
        unsigned before = pref[t] - s;
        for (int j = 0; j < per; j++) {
            if (before < target && before + cnt[j] >= target) {
                sh_sel = (unsigned)(t * per + j);
                sh_tnext = target - before;
                sh_cb = before;
                sh_ci = before + cnt[j];
            }
            before += cnt[j];
        }
        __syncthreads();
        unsigned sel = sh_sel;
        unsigned long long ceb = 0, cei = 0;
        for (int j = 0; j < per; j++) {
            unsigned bin = (unsigned)(t * per + j);
            if (bin < sel)  ceb += cev[j];
            if (bin <= sel) cei += cev[j];
        }
        ceb = block_reduce(ceb, qscr);
        cei = block_reduce(cei, qscr);
        if (t == 0) {
            if (level == 1)      { c->sel1 = sel; c->target = sh_tnext; c->cnt_below = sh_cb; c->ce_below_fx = ceb; }
            else if (level == 2) { c->sel2 = sel; c->target = sh_tnext; c->cnt_below += sh_cb; c->ce_below_fx += ceb; }
            else {
                double ce1  = (double)(c->ce_below_fx + cei) / (double)CE_SCALE;
                double cntd = (double)c->pos_num + (double)(c->cnt_below + sh_ci);
                if (cntd < 1.0) cntd = 1.0;
                c->loss_score = (c->ce0 + ce1) / cntd;
                c->loss_bbox  = (c->ms > 0.0) ? (c->d2 / fmax(c->ms, 1e-8)) : 0.0;
            }
        }
        __syncthreads();
    }
    if (level == 3 && t == 0) {
        BranchCtrl* c0 = ctrl_of(ws, 0);
        BranchCtrl* c1 = ctrl_of(ws, 1);
        out[0] = (float)(c0->loss_score + c0->loss_bbox + c1->loss_score + c1->loss_bbox);
        out[1] = (float)c0->loss_score;
        out[2] = (float)c0->loss_bbox;
        out[3] = (float)c1->loss_score;
        out[4] = (float)c1->loss_bbox;
    }
}

// ---------------- host ----------------
template <bool S>
static void run_pipeline(const float4* sc0, const float4* bb0, const float4* mk0, const float4* lb0,
                         const float4* sc1, const float4* bb1, const float4* mk1, const float4* lb1,
                         void* ws, float* out, hipStream_t stream)
{
    main_pass<S><<<GRID_M, BLK, 0, stream>>>(sc0, bb0, mk0, lb0, sc1, bb1, mk1, lb1, ws);
    scan_pass<<<1, BLK, 0, stream>>>(ws, 1, out);
    refine_pass<S><<<GRID_R, BLK, 0, stream>>>(sc0, lb0, sc1, lb1, ws, 2);
    scan_pass<<<1, BLK, 0, stream>>>(ws, 2, out);
    refine_pass<S><<<GRID_R, BLK, 0, stream>>>(sc0, lb0, sc1, lb1, ws, 3);
    scan_pass<<<1, BLK, 0, stream>>>(ws, 3, out);
}

extern "C" void kernel_launch(void* const* d_in, const int* in_sizes, int n_in,
                              void* d_out, int out_size, void* d_ws, size_t ws_size,
                              hipStream_t stream)
{
    (void)in_sizes; (void)n_in; (void)out_size;
    const float4* sc0 = (const float4*)d_in[0];
    const float4* bb0 = (const float4*)d_in[1];
    const float4* mk0 = (const float4*)d_in[2];
    const float4* lb0 = (const float4*)d_in[3];
    const float4* sc1 = (const float4*)d_in[4];
    const float4* bb1 = (const float4*)d_in[5];
    const float4* mk1 = (const float4*)d_in[6];
    const float4* lb1 = (const float4*)d_in[7];
    float* out = (float*)d_out;

    zero_ws_k<<<(ZERO_WORDS + BLK - 1) / BLK, BLK, 0, stream>>>((unsigned*)d_ws, ZERO_WORDS);

    if (ws_size >= WS_NEED)
        run_pipeline<true>(sc0, bb0, mk0, lb0, sc1, bb1, mk1, lb1, d_ws, out, stream);
    else
        run_pipeline<false>(sc0, bb0, mk0, lb0, sc1, bb1, mk1, lb1, d_ws, out, stream);
}